// Round 7
// baseline (233.692 us; speedup 1.0000x reference)
//
#include <hip/hip_runtime.h>

// Inverse wavelet transform (Haar):
//   x: [4B, C, H, W] fp32 with B=8, C=64, H=128, W=128
//   out: [B, C, 2H, 2W] fp32
//
// Round-7 (= round-5/6 resubmitted after broker timeouts): deep-ILP
// grid-stride. Rounds 2/4 (one-shot threads, ~2 KB in flight per wave)
// both stuck at ~80 us / 2.5 TB/s regardless of load/store pattern ->
// latency-exposed, not pattern-bound. This version:
//   2048 blocks x 256 threads, ITERS=4 units/thread,
//   all 16 float4 loads batched (256 B/thread, 16 KB/wave in flight)
//   before the compute+store phase.

constexpr int H = 128, W = 128;
constexpr int HW = H * W;             // 16384 (per-channel input plane)
constexpr int OUT_ROW = 2 * W;        // 256 floats per output row
constexpr int OUT_PLANE = 4 * HW;     // 65536 floats per (b,c) output plane
constexpr int ITERS = 4;

__global__ __launch_bounds__(256) void iwt_kernel(const float* __restrict__ x,
                                                  float* __restrict__ out,
                                                  int quarter,     // elems per input quarter
                                                  int total_units) // float4-columns of input
{
    const int tid0   = blockIdx.x * blockDim.x + threadIdx.x;
    const int stride = gridDim.x * blockDim.x;
    const int last   = total_units - 1;

    float4 a[ITERS][4];
    int    u[ITERS];

    // Phase 1: issue all 16 loads (no dependent use -> all in flight).
#pragma unroll
    for (int k = 0; k < ITERS; ++k) {
        int uk = tid0 + k * stride;
        if (uk > last) uk = last;          // benign duplicate on tail (none: exact division)
        u[k] = uk;
        int jv = uk & 31;                  // W/4 = 32 float4-columns
        int i  = (uk >> 5) & (H - 1);
        int cb = uk >> 12;                 // b*C + c
        int in_off = cb * HW + i * W + (jv << 2);
        a[k][0] = *reinterpret_cast<const float4*>(x + in_off);
        a[k][1] = *reinterpret_cast<const float4*>(x + in_off + quarter);
        a[k][2] = *reinterpret_cast<const float4*>(x + in_off + 2 * quarter);
        a[k][3] = *reinterpret_cast<const float4*>(x + in_off + 3 * quarter);
    }

    // Phase 2: compute + store.
#pragma unroll
    for (int k = 0; k < ITERS; ++k) {
        int uk = u[k];
        int jv = uk & 31;
        int i  = (uk >> 5) & (H - 1);
        int cb = uk >> 12;

        float v1[4] = {a[k][0].x, a[k][0].y, a[k][0].z, a[k][0].w};
        float v2[4] = {a[k][1].x, a[k][1].y, a[k][1].z, a[k][1].w};
        float v3[4] = {a[k][2].x, a[k][2].y, a[k][2].z, a[k][2].w};
        float v4[4] = {a[k][3].x, a[k][3].y, a[k][3].z, a[k][3].w};

        float top[8], bot[8];
#pragma unroll
        for (int c = 0; c < 4; ++c) {
            float s1 = v1[c] * 0.5f;
            float s2 = v2[c] * 0.5f;
            float s3 = v3[c] * 0.5f;
            float s4 = v4[c] * 0.5f;
            top[2 * c + 0] = s1 - s2 - s3 + s4;  // e00
            top[2 * c + 1] = s1 + s2 - s3 - s4;  // e01
            bot[2 * c + 0] = s1 - s2 + s3 - s4;  // e10
            bot[2 * c + 1] = s1 + s2 + s3 + s4;  // e11
        }

        int out_top = cb * OUT_PLANE + (2 * i) * OUT_ROW + (jv << 3);
        int out_bot = out_top + OUT_ROW;

        *reinterpret_cast<float4*>(out + out_top)     = make_float4(top[0], top[1], top[2], top[3]);
        *reinterpret_cast<float4*>(out + out_top + 4) = make_float4(top[4], top[5], top[6], top[7]);
        *reinterpret_cast<float4*>(out + out_bot)     = make_float4(bot[0], bot[1], bot[2], bot[3]);
        *reinterpret_cast<float4*>(out + out_bot + 4) = make_float4(bot[4], bot[5], bot[6], bot[7]);
    }
}

extern "C" void kernel_launch(void* const* d_in, const int* in_sizes, int n_in,
                              void* d_out, int out_size, void* d_ws, size_t ws_size,
                              hipStream_t stream) {
    const float* x = (const float*)d_in[0];
    float* out = (float*)d_out;

    const int quarter     = in_sizes[0] / 4;   // 8,388,608
    const int total_units = out_size / 16;     // 2,097,152 float4-columns
    const int block = 256;
    const int grid  = (total_units + block * ITERS - 1) / (block * ITERS);  // 2048

    iwt_kernel<<<grid, block, 0, stream>>>(x, out, quarter, total_units);
}

// Round 8
// 226.645 us; speedup vs baseline: 1.0311x; 1.0311x over previous
//
#include <hip/hip_runtime.h>

// Inverse wavelet transform (Haar):
//   x: [4B, C, H, W] fp32 with B=8, C=64, H=128, W=128
//   out: [B, C, 2H, 2W] fp32
//
// Round-8: round-4 structure (one thread per float2 input column-pair,
// contiguous float4 stores) + NONTEMPORAL stores. Rounds 2/4/7 ruled out
// store pattern, load width, in-flight depth, occupancy, launch overhead
// (8x wave-count variation, zero perf change; fillBuffer hits 6.7 TB/s in
// the same graph). Remaining theory: streaming writes allocate in L2/L3
// (output freshly poisoned = dirty lines), evict/writeback churn competes
// with the read stream. nt stores bypass allocation; loads stay cached
// (50% of reads hit L3).

typedef float f2 __attribute__((ext_vector_type(2)));
typedef float f4 __attribute__((ext_vector_type(4)));

constexpr int H = 128, W = 128;
constexpr int HW = H * W;             // 16384 (per-channel input plane)
constexpr int OUT_ROW = 2 * W;        // 256 floats per output row
constexpr int OUT_PLANE = 4 * HW;     // 65536 floats per (b,c) output plane

__global__ __launch_bounds__(256) void iwt_kernel(const float* __restrict__ x,
                                                  float* __restrict__ out,
                                                  int quarter,   // elems per input quarter
                                                  int total_vec) // total worker threads
{
    int tid = blockIdx.x * blockDim.x + threadIdx.x;
    if (tid >= total_vec) return;

    // tid = ((b*C + c)*H + i)*(W/2) + jv2
    int jv2 = tid & 63;              // W/2 = 64 float2-columns
    int i   = (tid >> 6) & (H - 1);  // H = 128
    int cb  = tid >> 13;             // b*C + c

    int in_off = cb * HW + i * W + (jv2 << 1);

    const f2 a1 = *reinterpret_cast<const f2*>(x + in_off);
    const f2 a2 = *reinterpret_cast<const f2*>(x + in_off + quarter);
    const f2 a3 = *reinterpret_cast<const f2*>(x + in_off + 2 * quarter);
    const f2 a4 = *reinterpret_cast<const f2*>(x + in_off + 3 * quarter);

    // column 0
    float s1 = a1[0] * 0.5f, s2 = a2[0] * 0.5f, s3 = a3[0] * 0.5f, s4 = a4[0] * 0.5f;
    float e00a = s1 - s2 - s3 + s4;
    float e01a = s1 + s2 - s3 - s4;
    float e10a = s1 - s2 + s3 - s4;
    float e11a = s1 + s2 + s3 + s4;
    // column 1
    float t1 = a1[1] * 0.5f, t2 = a2[1] * 0.5f, t3 = a3[1] * 0.5f, t4 = a4[1] * 0.5f;
    float e00b = t1 - t2 - t3 + t4;
    float e01b = t1 + t2 - t3 - t4;
    float e10b = t1 - t2 + t3 - t4;
    float e11b = t1 + t2 + t3 + t4;

    int out_top = cb * OUT_PLANE + (2 * i) * OUT_ROW + (jv2 << 2);
    int out_bot = out_top + OUT_ROW;

    f4 vt = {e00a, e01a, e00b, e01b};
    f4 vb = {e10a, e11a, e10b, e11b};

    __builtin_nontemporal_store(vt, reinterpret_cast<f4*>(out + out_top));
    __builtin_nontemporal_store(vb, reinterpret_cast<f4*>(out + out_bot));
}

extern "C" void kernel_launch(void* const* d_in, const int* in_sizes, int n_in,
                              void* d_out, int out_size, void* d_ws, size_t ws_size,
                              hipStream_t stream) {
    const float* x = (const float*)d_in[0];
    float* out = (float*)d_out;

    const int quarter   = in_sizes[0] / 4;   // 8,388,608
    const int total_vec = out_size / 8;      // 8 output floats per thread -> 4,194,304
    const int block = 256;
    const int grid  = (total_vec + block - 1) / block;  // 16384

    iwt_kernel<<<grid, block, 0, stream>>>(x, out, quarter, total_vec);
}